// Round 2
// baseline (154569.336 us; speedup 1.0000x reference)
//
#include <hip/hip_runtime.h>

typedef __attribute__((ext_vector_type(8))) short bf16x8;
typedef __attribute__((ext_vector_type(4))) float f32x4;

#define Tn 1024
#define Bn 64
#define Hn 2048
#define NBLK 256
#define NTHR 512

__device__ __forceinline__ unsigned short f2b(float x) {
    // fp32 -> bf16 round-to-nearest-even
    unsigned u = __float_as_uint(x);
    return (unsigned short)((u + 0x7fffu + ((u >> 16) & 1u)) >> 16);
}
__device__ __forceinline__ float sigm(float x) {
    return __builtin_amdgcn_rcpf(1.0f + __expf(-x));
}
__device__ __forceinline__ float tanh_f(float x) {
    float e = __expf(2.0f * x);
    return 1.0f - 2.0f * __builtin_amdgcn_rcpf(1.0f + e);
}

// Prep: init_hidden fp32 -> bf16 h0; zero barrier control area.
__global__ void prep_kernel(const float* __restrict__ init_h,
                            unsigned short* __restrict__ h0,
                            unsigned* __restrict__ ctrl) {
    const int i = blockIdx.x * 256 + threadIdx.x;
    const long i4 = (long)i * 4;
    if (i4 < 131072L) {
        float4 v = *reinterpret_cast<const float4*>(init_h + i4);
        ushort4 o;
        o.x = f2b(v.x); o.y = f2b(v.y); o.z = f2b(v.z); o.w = f2b(v.w);
        *reinterpret_cast<ushort4*>(h0 + i4) = o;
    }
    if (i < 2048) ctrl[i] = 0u;
}

// Persistent GRU. 256 blocks x 512 threads (8 waves).
// Block bk owns hidden units j in [8*bk, 8*bk+8).
// Wave w (0..7) owns K-slice [256w, 256w+256); its W rows (B-frags) live in
// REGISTERS for the whole kernel (immune to per-step L2 invalidation).
// Per wave per step: 8 k-iters x 4 M-tiles x 2 N-tiles MFMA 16x16x32_bf16.
//   N-tile0 cols: 0-7 = r-gate rows (j0+n), 8-15 = z-gate rows (H+j0+n-8)
//   N-tile1 cols: 0-7 = n-gate rows (2H+j0+n), 8-15 = dup (ignored)
// Cross-wave K-reduction through LDS; wave m (m<4) reduces + epilogues M-tile m.
// fp32 hidden state in registers of waves 0-3 at MFMA C-layout positions.
__global__ void __launch_bounds__(NTHR, 2) gru_kernel(
    const float* __restrict__ inp,     // [T][B][3]
    const float* __restrict__ init_h,  // [B][H]
    const float* __restrict__ w_ih,    // [3H][3]
    const float* __restrict__ w_hh,    // [3H][H] fp32
    const float* __restrict__ bias,    // [3H]
    const float* __restrict__ bias_n,  // [H]
    unsigned short* __restrict__ h0,   // [B][H] bf16 double buffer
    unsigned short* __restrict__ h1,
    unsigned* __restrict__ ctrl,       // [2048] barrier counters
    float* __restrict__ out)           // [T][B]
{
    __shared__ f32x4 red[8 * 4 * 2 * 64];  // [wave][mt][nt][lane] = 64 KB

    const int tid  = threadIdx.x;
    const int lane = tid & 63;
    const int w    = tid >> 6;      // wave id = K-slice owner
    const int quad = lane >> 4;
    const int n16  = lane & 15;
    const int jj   = n16 & 7;
    const int j0   = blockIdx.x * 8;
    const int jg   = j0 + jj;
    const int ks   = w * 256;
    const int mt_own = w & 3;       // epilogue M-tile for waves 0-3

    // B-frag source rows in W (fp32, row-major [3H][H])
    const int rowN0 = (n16 < 8) ? (j0 + n16) : (Hn + j0 + n16 - 8);
    const int rowN1 = 2 * Hn + j0 + jj;

    // ---- preload W rows into registers as bf16 B-fragments ----
    bf16x8 Bf0[8], Bf1[8];
    #pragma unroll
    for (int k = 0; k < 8; ++k) {
        const int koff = ks + k * 32 + quad * 8;
        const float* p0 = w_hh + (long)rowN0 * Hn + koff;
        const float* p1 = w_hh + (long)rowN1 * Hn + koff;
        bf16x8 b0, b1;
        #pragma unroll
        for (int j = 0; j < 8; ++j) {
            b0[j] = (short)f2b(p0[j]);
            b1[j] = (short)f2b(p1[j]);
        }
        Bf0[k] = b0;
        Bf1[k] = b1;
    }

    // Epilogue constants (used by waves 0-3, lanes n16<8)
    float wr0 = w_ih[jg*3+0], wr1 = w_ih[jg*3+1], wr2 = w_ih[jg*3+2];
    float wz0 = w_ih[(Hn+jg)*3+0], wz1 = w_ih[(Hn+jg)*3+1], wz2 = w_ih[(Hn+jg)*3+2];
    float wn0 = w_ih[(2*Hn+jg)*3+0], wn1 = w_ih[(2*Hn+jg)*3+1], wn2 = w_ih[(2*Hn+jg)*3+2];
    float br_ = bias[jg], bz_ = bias[Hn+jg], bn2_ = bias[2*Hn+jg];
    float bnn_ = bias_n[jg];

    // fp32 hidden state registers (waves 0-3; batch b = 16*w + quad*4 + r, col jg)
    float hst[4];
    #pragma unroll
    for (int r = 0; r < 4; ++r)
        hst[r] = init_h[(16 * mt_own + quad * 4 + r) * Hn + jg];

    unsigned* ctr = ctrl;            // 8 counters, 128 B apart: ctr[c*32]

    for (int t = 0; t < Tn; ++t) {
        const unsigned short* hcur = (t & 1) ? h1 : h0;
        unsigned short* hnext      = (t & 1) ? h0 : h1;

        // prefetch input projections' x for this step (overlaps with k-loop)
        float xv[4][3];
        if (w < 4) {
            #pragma unroll
            for (int r = 0; r < 4; ++r) {
                const float* xp = inp + ((long)t * Bn + 16 * w + quad * 4 + r) * 3;
                xv[r][0] = xp[0]; xv[r][1] = xp[1]; xv[r][2] = xp[2];
            }
        }

        f32x4 acc[4][2];
        #pragma unroll
        for (int mt = 0; mt < 4; ++mt) {
            acc[mt][0] = f32x4{0.f, 0.f, 0.f, 0.f};
            acc[mt][1] = f32x4{0.f, 0.f, 0.f, 0.f};
        }

        #pragma unroll 2
        for (int k = 0; k < 8; ++k) {
            const int koff = ks + k * 32 + quad * 8;
            #pragma unroll
            for (int mt = 0; mt < 4; ++mt) {
                bf16x8 a = *(const bf16x8*)(hcur + (16 * mt + n16) * Hn + koff);
                acc[mt][0] = __builtin_amdgcn_mfma_f32_16x16x32_bf16(a, Bf0[k], acc[mt][0], 0, 0, 0);
                acc[mt][1] = __builtin_amdgcn_mfma_f32_16x16x32_bf16(a, Bf1[k], acc[mt][1], 0, 0, 0);
            }
        }

        // dump partials to LDS
        #pragma unroll
        for (int mt = 0; mt < 4; ++mt) {
            red[((w * 4 + mt) * 2 + 0) * 64 + lane] = acc[mt][0];
            red[((w * 4 + mt) * 2 + 1) * 64 + lane] = acc[mt][1];
        }
        __syncthreads();

        if (w < 4) {
            // reduce over the 8 K-slices for M-tile mt_own
            f32x4 s0 = red[((0 * 4 + mt_own) * 2 + 0) * 64 + lane];
            f32x4 s1 = red[((0 * 4 + mt_own) * 2 + 1) * 64 + lane];
            #pragma unroll
            for (int ww = 1; ww < 8; ++ww) {
                s0 += red[((ww * 4 + mt_own) * 2 + 0) * 64 + lane];
                s1 += red[((ww * 4 + mt_own) * 2 + 1) * 64 + lane];
            }
            #pragma unroll
            for (int r = 0; r < 4; ++r) {
                float rdot = s0[r];
                float ndot = s1[r];
                float zdot = __shfl_xor(rdot, 8, 64);  // all lanes execute
                if (n16 < 8) {
                    const int b = 16 * mt_own + quad * 4 + r;
                    float pr = br_ + wr0*xv[r][0] + wr1*xv[r][1] + wr2*xv[r][2] + rdot;
                    float pz = bz_ + wz0*xv[r][0] + wz1*xv[r][1] + wz2*xv[r][2] + zdot;
                    float rr = sigm(pr);
                    float zz = sigm(pz);
                    float pn = bn2_ + wn0*xv[r][0] + wn1*xv[r][1] + wn2*xv[r][2] + rr * (ndot + bnn_);
                    float nn = tanh_f(pn);
                    float hv = nn + zz * (hst[r] - nn);
                    hst[r] = hv;
                    hnext[b * Hn + jg] = f2b(hv);
                    if (blockIdx.x == 0 && n16 == 0) out[t * Bn + b] = hv;
                }
            }
        }

        // ---- grid barrier: release fence, distributed arrive, relaxed poll ----
        __threadfence();   // per-wave: drain + write-back h stores (release)
        __syncthreads();   // all waves' fences complete before arrival
        if (tid == 0)
            __hip_atomic_fetch_add(&ctr[(blockIdx.x & 7) * 32], 1u,
                                   __ATOMIC_RELAXED, __HIP_MEMORY_SCOPE_AGENT);
        const unsigned tgt = (unsigned)(t + 1) * NBLK;
        if (tid == 0) {
            for (;;) {
                unsigned s = 0;
                #pragma unroll
                for (int c = 0; c < 8; ++c)
                    s += __hip_atomic_load(&ctr[c * 32], __ATOMIC_RELAXED,
                                           __HIP_MEMORY_SCOPE_AGENT);
                if (s >= tgt) break;
                __builtin_amdgcn_s_sleep(1);
            }
        }
        __syncthreads();
        __threadfence();   // acquire: invalidate so fresh h is visible
    }
}

extern "C" void kernel_launch(void* const* d_in, const int* in_sizes, int n_in,
                              void* d_out, int out_size, void* d_ws, size_t ws_size,
                              hipStream_t stream) {
    const float* inp    = (const float*)d_in[0];  // [1024][64][3]
    const float* init_h = (const float*)d_in[1];  // [64][2048]
    const float* w_ih   = (const float*)d_in[2];  // [6144][3]
    const float* w_hh   = (const float*)d_in[3];  // [6144][2048]
    const float* bias   = (const float*)d_in[4];  // [6144]
    const float* bias_n = (const float*)d_in[5];  // [2048]
    float* out = (float*)d_out;                   // [1024][64]

    unsigned short* h0 = (unsigned short*)d_ws;          // 262144 B
    unsigned short* h1 = h0 + 131072L;                   // 262144 B
    unsigned* ctrl     = (unsigned*)(h1 + 131072L);      // 8192 B

    prep_kernel<<<128, 256, 0, stream>>>(init_h, h0, ctrl);
    gru_kernel<<<NBLK, NTHR, 0, stream>>>(inp, init_h, w_ih, w_hh, bias, bias_n,
                                          h0, h1, ctrl, out);
}

// Round 3
// 153606.201 us; speedup vs baseline: 1.0063x; 1.0063x over previous
//
#include <hip/hip_runtime.h>

typedef __attribute__((ext_vector_type(8))) short bf16x8;
typedef __attribute__((ext_vector_type(4))) float f32x4;

#define Tn 1024
#define Bn 64
#define Hn 2048
#define NBLK 256
#define NTHR 512

#define LEAF_STRIDE 32     // 128 B apart
#define ROOT_IDX (32 * 32) // ctrl[1024]
#define FLAG_IDX (33 * 32) // ctrl[1056]

__device__ __forceinline__ unsigned short f2b(float x) {
    // fp32 -> bf16 round-to-nearest-even
    unsigned u = __float_as_uint(x);
    return (unsigned short)((u + 0x7fffu + ((u >> 16) & 1u)) >> 16);
}
__device__ __forceinline__ float sigm(float x) {
    return __builtin_amdgcn_rcpf(1.0f + __expf(-x));
}
__device__ __forceinline__ float tanh_f(float x) {
    float e = __expf(2.0f * x);
    return 1.0f - 2.0f * __builtin_amdgcn_rcpf(1.0f + e);
}

// h fragment layout: h_f[kk][mt][lane][e], kk=k>>5 (0..63), mt=b>>4 (0..3),
// lane=((k>>3)&3)*16 + (b&15), e=k&7.  One MFMA A-frag = 64 lanes x 16B contig.
__device__ __forceinline__ long hfrag_off(int b, int k) {
    return ((long)(((k >> 5) * 4 + (b >> 4)) * 64) + ((k >> 3) & 3) * 16 + (b & 15)) * 8 + (k & 7);
}

// Prep: init_hidden fp32 -> bf16 h0 in frag layout; zero barrier control area.
__global__ void prep_kernel(const float* __restrict__ init_h,
                            unsigned short* __restrict__ h0,
                            unsigned* __restrict__ ctrl) {
    const int i = blockIdx.x * 256 + threadIdx.x;  // 0..32767
    const int b  = i >> 9;
    const int k4 = (i & 511) << 2;                 // k, step 4 (e stays in {0,4})
    float4 v = *reinterpret_cast<const float4*>(init_h + (long)b * Hn + k4);
    ushort4 o;
    o.x = f2b(v.x); o.y = f2b(v.y); o.z = f2b(v.z); o.w = f2b(v.w);
    *reinterpret_cast<ushort4*>(h0 + hfrag_off(b, k4)) = o;
    if (i < 2048) ctrl[i] = 0u;
}

// Persistent GRU. 256 blocks x 512 threads (8 waves), 1 block/CU.
// Block bk owns hidden units j in [8*bk, 8*bk+8).
// Wave w (0..7) owns K-slice [256w, 256w+256); its W rows (B-frags) live in
// REGISTERS for the whole kernel (immune to per-step cache invalidation).
//   N-tile0 cols: 0-7 = r-gate rows (j0+n), 8-15 = z-gate rows (H+j0+n-8)
//   N-tile1 cols: 0-7 = n-gate rows (2H+j0+n), 8-15 = dup (ignored)
// Cross-wave K-reduction through LDS; wave m (m<4) reduces + epilogues M-tile m.
// fp32 hidden state in registers of waves 0-3 at MFMA C-layout positions.
// Grid barrier: tree arrivals (32 leaves -> root, relaxed agent RMWs = MALL
// atomics), root-closer publishes flag; pollers use sc0/sc1 bypass loads
// (fresh, NO buffer_inv) + s_sleep backoff. One threadfence per step each way.
__global__ void __launch_bounds__(NTHR, 2) gru_kernel(
    const float* __restrict__ inp,     // [T][B][3]
    const float* __restrict__ init_h,  // [B][H]
    const float* __restrict__ w_ih,    // [3H][3]
    const float* __restrict__ w_hh,    // [3H][H] fp32
    const float* __restrict__ bias,    // [3H]
    const float* __restrict__ bias_n,  // [H]
    unsigned short* __restrict__ h0,   // [B][H] bf16 frag-layout double buffer
    unsigned short* __restrict__ h1,
    unsigned* __restrict__ ctrl,       // [2048] barrier counters + flag
    float* __restrict__ out)           // [T][B]
{
    __shared__ f32x4 red[8 * 4 * 2 * 64];  // [wave][mt][nt][lane] = 64 KB

    const int tid  = threadIdx.x;
    const int lane = tid & 63;
    const int w    = tid >> 6;      // wave id = K-slice owner
    const int quad = lane >> 4;
    const int n16  = lane & 15;
    const int jj   = n16 & 7;
    const int j0   = blockIdx.x * 8;
    const int jg   = j0 + jj;
    const int ks   = w * 256;
    const int mt_own = w & 3;       // epilogue M-tile for waves 0-3

    // B-frag source rows in W (fp32, row-major [3H][H])
    const int rowN0 = (n16 < 8) ? (j0 + n16) : (Hn + j0 + n16 - 8);
    const int rowN1 = 2 * Hn + j0 + jj;

    // ---- preload W rows into registers as bf16 B-fragments (one-time) ----
    bf16x8 Bf0[8], Bf1[8];
    #pragma unroll
    for (int k = 0; k < 8; ++k) {
        const int koff = ks + k * 32 + quad * 8;
        const float* p0 = w_hh + (long)rowN0 * Hn + koff;
        const float* p1 = w_hh + (long)rowN1 * Hn + koff;
        bf16x8 b0, b1;
        #pragma unroll
        for (int j = 0; j < 8; ++j) {
            b0[j] = (short)f2b(p0[j]);
            b1[j] = (short)f2b(p1[j]);
        }
        Bf0[k] = b0;
        Bf1[k] = b1;
    }

    // Epilogue constants (used by waves 0-3, lanes n16<8)
    float wr0 = w_ih[jg*3+0], wr1 = w_ih[jg*3+1], wr2 = w_ih[jg*3+2];
    float wz0 = w_ih[(Hn+jg)*3+0], wz1 = w_ih[(Hn+jg)*3+1], wz2 = w_ih[(Hn+jg)*3+2];
    float wn0 = w_ih[(2*Hn+jg)*3+0], wn1 = w_ih[(2*Hn+jg)*3+1], wn2 = w_ih[(2*Hn+jg)*3+2];
    float br_ = bias[jg], bz_ = bias[Hn+jg], bn2_ = bias[2*Hn+jg];
    float bnn_ = bias_n[jg];

    // fp32 hidden state registers (waves 0-3; batch b = 16*mt_own + quad*4 + r)
    float hst[4];
    #pragma unroll
    for (int r = 0; r < 4; ++r)
        hst[r] = init_h[(long)(16 * mt_own + quad * 4 + r) * Hn + jg];

    // Epilogue frag-store constants: j = 8*bid + jj
    const int kkE = blockIdx.x >> 2;   // j>>5
    const int qE  = blockIdx.x & 3;    // (j>>3)&3

    for (int t = 0; t < Tn; ++t) {
        const unsigned short* hcur = (t & 1) ? h1 : h0;
        unsigned short* hnext      = (t & 1) ? h0 : h1;

        // input contributions for this step (overlaps with k-loop)
        float xv[4][3];
        if (w < 4) {
            #pragma unroll
            for (int r = 0; r < 4; ++r) {
                const float* xp = inp + ((long)t * Bn + 16 * w + quad * 4 + r) * 3;
                xv[r][0] = xp[0]; xv[r][1] = xp[1]; xv[r][2] = xp[2];
            }
        }

        f32x4 acc[4][2];
        #pragma unroll
        for (int mt = 0; mt < 4; ++mt) {
            acc[mt][0] = f32x4{0.f, 0.f, 0.f, 0.f};
            acc[mt][1] = f32x4{0.f, 0.f, 0.f, 0.f};
        }

        #pragma unroll 2
        for (int k = 0; k < 8; ++k) {
            #pragma unroll
            for (int mt = 0; mt < 4; ++mt) {
                // coalesced frag-layout A load: 64 lanes x 16B contiguous
                bf16x8 a = *(const bf16x8*)(hcur + ((((w * 8 + k) * 4 + mt) * 64) + lane) * 8);
                acc[mt][0] = __builtin_amdgcn_mfma_f32_16x16x32_bf16(a, Bf0[k], acc[mt][0], 0, 0, 0);
                acc[mt][1] = __builtin_amdgcn_mfma_f32_16x16x32_bf16(a, Bf1[k], acc[mt][1], 0, 0, 0);
            }
        }

        // dump partials to LDS
        #pragma unroll
        for (int mt = 0; mt < 4; ++mt) {
            red[((w * 4 + mt) * 2 + 0) * 64 + lane] = acc[mt][0];
            red[((w * 4 + mt) * 2 + 1) * 64 + lane] = acc[mt][1];
        }
        __syncthreads();

        if (w < 4) {
            // reduce over the 8 K-slices for M-tile mt_own
            f32x4 s0 = red[((0 * 4 + mt_own) * 2 + 0) * 64 + lane];
            f32x4 s1 = red[((0 * 4 + mt_own) * 2 + 1) * 64 + lane];
            #pragma unroll
            for (int ww = 1; ww < 8; ++ww) {
                s0 += red[((ww * 4 + mt_own) * 2 + 0) * 64 + lane];
                s1 += red[((ww * 4 + mt_own) * 2 + 1) * 64 + lane];
            }
            #pragma unroll
            for (int r = 0; r < 4; ++r) {
                float rdot = s0[r];
                float ndot = s1[r];
                float zdot = __shfl_xor(rdot, 8, 64);  // all lanes execute
                if (n16 < 8) {
                    const int b = 16 * mt_own + quad * 4 + r;
                    float pr = br_ + wr0*xv[r][0] + wr1*xv[r][1] + wr2*xv[r][2] + rdot;
                    float pz = bz_ + wz0*xv[r][0] + wz1*xv[r][1] + wz2*xv[r][2] + zdot;
                    float rr = sigm(pr);
                    float zz = sigm(pz);
                    float pn = bn2_ + wn0*xv[r][0] + wn1*xv[r][1] + wn2*xv[r][2] + rr * (ndot + bnn_);
                    float nn = tanh_f(pn);
                    float hv = nn + zz * (hst[r] - nn);
                    hst[r] = hv;
                    // frag-layout store: laneF = qE*16 + (b&15), mtF = mt_own, e = jj
                    hnext[((long)((kkE * 4 + mt_own) * 64) + qE * 16 + quad * 4 + r) * 8 + jj] = f2b(hv);
                    if (blockIdx.x == 0 && n16 == 0) out[t * Bn + b] = hv;
                }
            }
        }

        // ---- grid barrier ----
        __threadfence();   // release: drain + write back h stores to MALL
        __syncthreads();   // all waves' fences complete before arrival
        if (tid == 0) {
            unsigned old = __hip_atomic_fetch_add(&ctrl[(blockIdx.x >> 3) * LEAF_STRIDE], 1u,
                                                  __ATOMIC_RELAXED, __HIP_MEMORY_SCOPE_AGENT);
            if ((old & 7) == 7) {
                unsigned old2 = __hip_atomic_fetch_add(&ctrl[ROOT_IDX], 1u,
                                                       __ATOMIC_RELAXED, __HIP_MEMORY_SCOPE_AGENT);
                if ((old2 & 31) == 31) {
                    __hip_atomic_store(&ctrl[FLAG_IDX], (unsigned)(t + 1),
                                       __ATOMIC_RELAXED, __HIP_MEMORY_SCOPE_AGENT);
                }
            }
            const unsigned* fp = &ctrl[FLAG_IDX];
            const unsigned tgt = (unsigned)(t + 1);
            for (;;) {
                unsigned v;
                // cache-BYPASS load (sc0 sc1): fresh from MALL, no buffer_inv
                asm volatile("global_load_dword %0, %1, off sc0 sc1\n\t"
                             "s_waitcnt vmcnt(0)"
                             : "=v"(v) : "v"(fp) : "memory");
                if (v >= tgt) break;
                __builtin_amdgcn_s_sleep(4);
            }
        }
        __syncthreads();
        __threadfence();   // acquire: invalidate caches so fresh h is visible
    }
}

extern "C" void kernel_launch(void* const* d_in, const int* in_sizes, int n_in,
                              void* d_out, int out_size, void* d_ws, size_t ws_size,
                              hipStream_t stream) {
    const float* inp    = (const float*)d_in[0];  // [1024][64][3]
    const float* init_h = (const float*)d_in[1];  // [64][2048]
    const float* w_ih   = (const float*)d_in[2];  // [6144][3]
    const float* w_hh   = (const float*)d_in[3];  // [6144][2048]
    const float* bias   = (const float*)d_in[4];  // [6144]
    const float* bias_n = (const float*)d_in[5];  // [2048]
    float* out = (float*)d_out;                   // [1024][64]

    unsigned short* h0 = (unsigned short*)d_ws;          // 262144 B
    unsigned short* h1 = h0 + 131072L;                   // 262144 B
    unsigned* ctrl     = (unsigned*)(h1 + 131072L);      // 8192 B

    prep_kernel<<<128, 256, 0, stream>>>(init_h, h0, ctrl);
    gru_kernel<<<NBLK, NTHR, 0, stream>>>(inp, init_h, w_ih, w_hh, bias, bias_n,
                                          h0, h1, ctrl, out);
}

// Round 4
// 152149.426 us; speedup vs baseline: 1.0159x; 1.0096x over previous
//
#include <hip/hip_runtime.h>

typedef __attribute__((ext_vector_type(8))) short bf16x8;
typedef __attribute__((ext_vector_type(4))) float f32x4;

#define Tn 1024
#define Bn 64
#define Hn 2048
#define NBLK 256
#define NTHR 512

#define LEAF_STRIDE 32     // 128 B apart
#define ROOT_IDX (32 * 32) // ctrl[1024]
#define FLAG_IDX (33 * 32) // ctrl[1056]

__device__ __forceinline__ unsigned short f2b(float x) {
    // fp32 -> bf16 round-to-nearest-even
    unsigned u = __float_as_uint(x);
    return (unsigned short)((u + 0x7fffu + ((u >> 16) & 1u)) >> 16);
}
__device__ __forceinline__ float sigm(float x) {
    return __builtin_amdgcn_rcpf(1.0f + __expf(-x));
}
__device__ __forceinline__ float tanh_f(float x) {
    float e = __expf(2.0f * x);
    return 1.0f - 2.0f * __builtin_amdgcn_rcpf(1.0f + e);
}

// h fragment layout: h_f[kk][mt][lane][e], kk=k>>5 (0..63), mt=b>>4 (0..3),
// lane=((k>>3)&3)*16 + (b&15), e=k&7.  One MFMA A-frag = 64 lanes x 16B contig.
__device__ __forceinline__ long hfrag_off(int b, int k) {
    return ((long)(((k >> 5) * 4 + (b >> 4)) * 64) + ((k >> 3) & 3) * 16 + (b & 15)) * 8 + (k & 7);
}

// Prep: init_hidden fp32 -> bf16 h0 in frag layout; zero barrier control area.
__global__ void prep_kernel(const float* __restrict__ init_h,
                            unsigned short* __restrict__ h0,
                            unsigned* __restrict__ ctrl) {
    const int i = blockIdx.x * 256 + threadIdx.x;  // 0..32767
    const int b  = i >> 9;
    const int k4 = (i & 511) << 2;                 // k, step 4 (e stays in {0,4})
    float4 v = *reinterpret_cast<const float4*>(init_h + (long)b * Hn + k4);
    ushort4 o;
    o.x = f2b(v.x); o.y = f2b(v.y); o.z = f2b(v.z); o.w = f2b(v.w);
    *reinterpret_cast<ushort4*>(h0 + hfrag_off(b, k4)) = o;
    if (i < 2048) ctrl[i] = 0u;
}

// Persistent GRU. 256 blocks x 512 threads (8 waves), 1 block/CU.
// Block bk owns hidden units j in [8*bk, 8*bk+8).
// Wave w (0..7) owns K-slice [256w, 256w+256); its W rows (B-frags) live in
// REGISTERS for the whole kernel (immune to per-step cache invalidation).
//   N-tile0 cols: 0-7 = r-gate rows (j0+n), 8-15 = z-gate rows (H+j0+n-8)
//   N-tile1 cols: 0-7 = n-gate rows (2H+j0+n), 8-15 = dup (ignored)
// Cross-wave K-reduction through LDS; wave m (m<4) reduces + epilogues M-tile m.
// fp32 hidden state in registers of waves 0-3 at MFMA C-layout positions.
// Grid barrier rules learned R1-R3 (MI355X cross-XCD coherence):
//   - producers must use atomic RMWs (always executed at MALL; plain/relaxed
//     stores linger dirty in the local XCD L2 and are invisible for ~100 us)
//   - consumers must use sc0/sc1 bypass loads (fresh from MALL, NO buffer_inv;
//     relaxed loads spin on the stale local L2 copy)
__global__ void __launch_bounds__(NTHR, 2) gru_kernel(
    const float* __restrict__ inp,     // [T][B][3]
    const float* __restrict__ init_h,  // [B][H]
    const float* __restrict__ w_ih,    // [3H][3]
    const float* __restrict__ w_hh,    // [3H][H] fp32
    const float* __restrict__ bias,    // [3H]
    const float* __restrict__ bias_n,  // [H]
    unsigned short* __restrict__ h0,   // [B][H] bf16 frag-layout double buffer
    unsigned short* __restrict__ h1,
    unsigned* __restrict__ ctrl,       // [2048] barrier counters + flag
    float* __restrict__ out)           // [T][B]
{
    __shared__ f32x4 red[8 * 4 * 2 * 64];  // [wave][mt][nt][lane] = 64 KB

    const int tid  = threadIdx.x;
    const int lane = tid & 63;
    const int w    = tid >> 6;      // wave id = K-slice owner
    const int quad = lane >> 4;
    const int n16  = lane & 15;
    const int jj   = n16 & 7;
    const int j0   = blockIdx.x * 8;
    const int jg   = j0 + jj;
    const int ks   = w * 256;
    const int mt_own = w & 3;       // epilogue M-tile for waves 0-3

    // B-frag source rows in W (fp32, row-major [3H][H])
    const int rowN0 = (n16 < 8) ? (j0 + n16) : (Hn + j0 + n16 - 8);
    const int rowN1 = 2 * Hn + j0 + jj;

    // ---- preload W rows into registers as bf16 B-fragments (one-time) ----
    bf16x8 Bf0[8], Bf1[8];
    #pragma unroll
    for (int k = 0; k < 8; ++k) {
        const int koff = ks + k * 32 + quad * 8;
        const float* p0 = w_hh + (long)rowN0 * Hn + koff;
        const float* p1 = w_hh + (long)rowN1 * Hn + koff;
        bf16x8 b0, b1;
        #pragma unroll
        for (int j = 0; j < 8; ++j) {
            b0[j] = (short)f2b(p0[j]);
            b1[j] = (short)f2b(p1[j]);
        }
        Bf0[k] = b0;
        Bf1[k] = b1;
    }

    // Epilogue constants (used by waves 0-3, lanes n16<8)
    float wr0 = w_ih[jg*3+0], wr1 = w_ih[jg*3+1], wr2 = w_ih[jg*3+2];
    float wz0 = w_ih[(Hn+jg)*3+0], wz1 = w_ih[(Hn+jg)*3+1], wz2 = w_ih[(Hn+jg)*3+2];
    float wn0 = w_ih[(2*Hn+jg)*3+0], wn1 = w_ih[(2*Hn+jg)*3+1], wn2 = w_ih[(2*Hn+jg)*3+2];
    float br_ = bias[jg], bz_ = bias[Hn+jg], bn2_ = bias[2*Hn+jg];
    float bnn_ = bias_n[jg];

    // fp32 hidden state registers (waves 0-3; batch b = 16*mt_own + quad*4 + r)
    float hst[4];
    #pragma unroll
    for (int r = 0; r < 4; ++r)
        hst[r] = init_h[(long)(16 * mt_own + quad * 4 + r) * Hn + jg];

    // Epilogue frag-store constants: j = 8*bid + jj
    const int kkE = blockIdx.x >> 2;   // j>>5
    const int qE  = blockIdx.x & 3;    // (j>>3)&3

    for (int t = 0; t < Tn; ++t) {
        const unsigned short* hcur = (t & 1) ? h1 : h0;
        unsigned short* hnext      = (t & 1) ? h0 : h1;

        // input contributions for this step (overlaps with k-loop)
        float xv[4][3];
        if (w < 4) {
            #pragma unroll
            for (int r = 0; r < 4; ++r) {
                const float* xp = inp + ((long)t * Bn + 16 * w + quad * 4 + r) * 3;
                xv[r][0] = xp[0]; xv[r][1] = xp[1]; xv[r][2] = xp[2];
            }
        }

        f32x4 acc[4][2];
        #pragma unroll
        for (int mt = 0; mt < 4; ++mt) {
            acc[mt][0] = f32x4{0.f, 0.f, 0.f, 0.f};
            acc[mt][1] = f32x4{0.f, 0.f, 0.f, 0.f};
        }

        #pragma unroll 2
        for (int k = 0; k < 8; ++k) {
            #pragma unroll
            for (int mt = 0; mt < 4; ++mt) {
                // coalesced frag-layout A load: 64 lanes x 16B contiguous
                bf16x8 a = *(const bf16x8*)(hcur + ((((w * 8 + k) * 4 + mt) * 64) + lane) * 8);
                acc[mt][0] = __builtin_amdgcn_mfma_f32_16x16x32_bf16(a, Bf0[k], acc[mt][0], 0, 0, 0);
                acc[mt][1] = __builtin_amdgcn_mfma_f32_16x16x32_bf16(a, Bf1[k], acc[mt][1], 0, 0, 0);
            }
        }

        // dump partials to LDS
        #pragma unroll
        for (int mt = 0; mt < 4; ++mt) {
            red[((w * 4 + mt) * 2 + 0) * 64 + lane] = acc[mt][0];
            red[((w * 4 + mt) * 2 + 1) * 64 + lane] = acc[mt][1];
        }
        __syncthreads();

        if (w < 4) {
            // reduce over the 8 K-slices for M-tile mt_own
            f32x4 s0 = red[((0 * 4 + mt_own) * 2 + 0) * 64 + lane];
            f32x4 s1 = red[((0 * 4 + mt_own) * 2 + 1) * 64 + lane];
            #pragma unroll
            for (int ww = 1; ww < 8; ++ww) {
                s0 += red[((ww * 4 + mt_own) * 2 + 0) * 64 + lane];
                s1 += red[((ww * 4 + mt_own) * 2 + 1) * 64 + lane];
            }
            #pragma unroll
            for (int r = 0; r < 4; ++r) {
                float rdot = s0[r];
                float ndot = s1[r];
                float zdot = __shfl_xor(rdot, 8, 64);  // all lanes execute
                if (n16 < 8) {
                    const int b = 16 * mt_own + quad * 4 + r;
                    float pr = br_ + wr0*xv[r][0] + wr1*xv[r][1] + wr2*xv[r][2] + rdot;
                    float pz = bz_ + wz0*xv[r][0] + wz1*xv[r][1] + wz2*xv[r][2] + zdot;
                    float rr = sigm(pr);
                    float zz = sigm(pz);
                    float pn = bn2_ + wn0*xv[r][0] + wn1*xv[r][1] + wn2*xv[r][2] + rr * (ndot + bnn_);
                    float nn = tanh_f(pn);
                    float hv = nn + zz * (hst[r] - nn);
                    hst[r] = hv;
                    // frag-layout store: laneF = qE*16 + (b&15), mtF = mt_own, e = jj
                    hnext[((long)((kkE * 4 + mt_own) * 64) + qE * 16 + quad * 4 + r) * 8 + jj] = f2b(hv);
                    if (blockIdx.x == 0 && n16 == 0) out[t * Bn + b] = hv;
                }
            }
        }

        // ---- grid barrier ----
        __threadfence();   // release: drain + write back h stores to MALL
        __syncthreads();   // all waves' fences complete before arrival
        if (tid == 0) {
            unsigned old = __hip_atomic_fetch_add(&ctrl[(blockIdx.x >> 3) * LEAF_STRIDE], 1u,
                                                  __ATOMIC_RELAXED, __HIP_MEMORY_SCOPE_AGENT);
            if ((old & 7) == 7) {
                unsigned old2 = __hip_atomic_fetch_add(&ctrl[ROOT_IDX], 1u,
                                                       __ATOMIC_RELAXED, __HIP_MEMORY_SCOPE_AGENT);
                if ((old2 & 31) == 31) {
                    // PUBLISH VIA RMW: atomics execute at the MALL coherence
                    // point (proven by R2/R3 never deadlocking); a relaxed
                    // atomic_store stays dirty in local L2 (~150us stale!).
                    __hip_atomic_fetch_add(&ctrl[FLAG_IDX], 1u,
                                           __ATOMIC_RELAXED, __HIP_MEMORY_SCOPE_AGENT);
                }
            }
            const unsigned* fp = &ctrl[FLAG_IDX];
            const unsigned tgt = (unsigned)(t + 1);
            for (;;) {
                unsigned v;
                // cache-BYPASS load (sc0 sc1): fresh from MALL, no buffer_inv
                asm volatile("global_load_dword %0, %1, off sc0 sc1\n\t"
                             "s_waitcnt vmcnt(0)"
                             : "=v"(v) : "v"(fp) : "memory");
                if (v >= tgt) break;
                __builtin_amdgcn_s_sleep(2);
            }
        }
        __syncthreads();
        __threadfence();   // acquire: invalidate caches so fresh h is visible
    }
}

extern "C" void kernel_launch(void* const* d_in, const int* in_sizes, int n_in,
                              void* d_out, int out_size, void* d_ws, size_t ws_size,
                              hipStream_t stream) {
    const float* inp    = (const float*)d_in[0];  // [1024][64][3]
    const float* init_h = (const float*)d_in[1];  // [64][2048]
    const float* w_ih   = (const float*)d_in[2];  // [6144][3]
    const float* w_hh   = (const float*)d_in[3];  // [6144][2048]
    const float* bias   = (const float*)d_in[4];  // [6144]
    const float* bias_n = (const float*)d_in[5];  // [2048]
    float* out = (float*)d_out;                   // [1024][64]

    unsigned short* h0 = (unsigned short*)d_ws;          // 262144 B
    unsigned short* h1 = h0 + 131072L;                   // 262144 B
    unsigned* ctrl     = (unsigned*)(h1 + 131072L);      // 8192 B

    prep_kernel<<<128, 256, 0, stream>>>(init_h, h0, ctrl);
    gru_kernel<<<NBLK, NTHR, 0, stream>>>(inp, init_h, w_ih, w_hh, bias, bias_n,
                                          h0, h1, ctrl, out);
}

// Round 5
// 99650.958 us; speedup vs baseline: 1.5511x; 1.5268x over previous
//
#include <hip/hip_runtime.h>

typedef __attribute__((ext_vector_type(8))) short bf16x8;
typedef __attribute__((ext_vector_type(4))) float f32x4;

#define Tn 1024
#define Bn 64
#define Hn 2048
#define NBLK 256
#define NTHR 512

#define LEAF_STRIDE 32     // 128 B apart
#define ROOT_IDX (32 * 32) // ctrl[1024]
#define FLAG_IDX (33 * 32) // ctrl[1056]

__device__ __forceinline__ unsigned short f2b(float x) {
    // fp32 -> bf16 round-to-nearest-even
    unsigned u = __float_as_uint(x);
    return (unsigned short)((u + 0x7fffu + ((u >> 16) & 1u)) >> 16);
}
__device__ __forceinline__ float sigm(float x) {
    return __builtin_amdgcn_rcpf(1.0f + __expf(-x));
}
__device__ __forceinline__ float tanh_f(float x) {
    float e = __expf(2.0f * x);
    return 1.0f - 2.0f * __builtin_amdgcn_rcpf(1.0f + e);
}

// system-scope write-through store (reaches MALL when vmcnt retires; no wbl2
// needed, and immune to buffer_inv dropping dirty L2 lines)
__device__ __forceinline__ void store_short_wt(unsigned short* p, unsigned v) {
    asm volatile("global_store_short %0, %1, off sc0 sc1"
                 :: "v"(p), "v"(v) : "memory");
}
__device__ __forceinline__ void store_dword_wt(float* p, float v) {
    asm volatile("global_store_dword %0, %1, off sc0 sc1"
                 :: "v"(p), "v"(__float_as_uint(v)) : "memory");
}

// h fragment layout: h_f[kk][mt][lane][e], kk=k>>5 (0..63), mt=b>>4 (0..3),
// lane=((k>>3)&3)*16 + (b&15), e=k&7.  One MFMA A-frag = 64 lanes x 16B contig.
__device__ __forceinline__ long hfrag_off(int b, int k) {
    return ((long)(((k >> 5) * 4 + (b >> 4)) * 64) + ((k >> 3) & 3) * 16 + (b & 15)) * 8 + (k & 7);
}

// Prep: init_hidden fp32 -> bf16 h0 in frag layout; zero barrier control area.
__global__ void prep_kernel(const float* __restrict__ init_h,
                            unsigned short* __restrict__ h0,
                            unsigned* __restrict__ ctrl) {
    const int i = blockIdx.x * 256 + threadIdx.x;  // 0..32767
    const int b  = i >> 9;
    const int k4 = (i & 511) << 2;                 // k, step 4 (e stays in {0,4})
    float4 v = *reinterpret_cast<const float4*>(init_h + (long)b * Hn + k4);
    ushort4 o;
    o.x = f2b(v.x); o.y = f2b(v.y); o.z = f2b(v.z); o.w = f2b(v.w);
    *reinterpret_cast<ushort4*>(h0 + hfrag_off(b, k4)) = o;
    if (i < 2048) ctrl[i] = 0u;
}

// Persistent GRU. 256 blocks x 512 threads (8 waves), 1 block/CU.
// Block bk owns hidden units j in [8*bk, 8*bk+8).
// Wave w (0..7) owns K-slice [256w, 256w+256); its W rows (B-frags) live in
// REGISTERS for the whole kernel.
// Cross-wave K-reduction through LDS; wave m (m<4) reduces + epilogues M-tile m.
// fp32 hidden state in registers of waves 0-3 at MFMA C-layout positions.
//
// Coherence protocol (R1-R4 lessons):
//   - NO __threadfence in the loop: agent fences emit buffer_wbl2/buffer_inv
//     PER WAVE, serializing at the XCD L2 (~150us/step at 2048 waves = R2-R4;
//     ~63us at 1024 waves = R1). That was the entire bottleneck.
//   - release: h/out stores are sc0/sc1 write-through (at MALL when vmcnt
//     retires; __syncthreads drains vmcnt before s_barrier) -> arrival RMW.
//   - producers of control data: atomic RMWs (execute at MALL).
//   - consumers: sc0/sc1 bypass loads (fresh, no invalidate).
//   - acquire: ONE buffer_inv sc1 per BLOCK per step (tid0 after flag detect).
__global__ void __launch_bounds__(NTHR, 2) gru_kernel(
    const float* __restrict__ inp,     // [T][B][3]
    const float* __restrict__ init_h,  // [B][H]
    const float* __restrict__ w_ih,    // [3H][3]
    const float* __restrict__ w_hh,    // [3H][H] fp32
    const float* __restrict__ bias,    // [3H]
    const float* __restrict__ bias_n,  // [H]
    unsigned short* __restrict__ h0,   // [B][H] bf16 frag-layout double buffer
    unsigned short* __restrict__ h1,
    unsigned* __restrict__ ctrl,       // [2048] barrier counters + flag
    float* __restrict__ out)           // [T][B]
{
    __shared__ f32x4 red[8 * 4 * 2 * 64];  // [wave][mt][nt][lane] = 64 KB

    const int tid  = threadIdx.x;
    const int lane = tid & 63;
    const int w    = tid >> 6;      // wave id = K-slice owner
    const int quad = lane >> 4;
    const int n16  = lane & 15;
    const int jj   = n16 & 7;
    const int j0   = blockIdx.x * 8;
    const int jg   = j0 + jj;
    const int ks   = w * 256;
    const int mt_own = w & 3;       // epilogue M-tile for waves 0-3

    // B-frag source rows in W (fp32, row-major [3H][H])
    const int rowN0 = (n16 < 8) ? (j0 + n16) : (Hn + j0 + n16 - 8);
    const int rowN1 = 2 * Hn + j0 + jj;

    // ---- preload W rows into registers as bf16 B-fragments (one-time) ----
    bf16x8 Bf0[8], Bf1[8];
    #pragma unroll
    for (int k = 0; k < 8; ++k) {
        const int koff = ks + k * 32 + quad * 8;
        const float* p0 = w_hh + (long)rowN0 * Hn + koff;
        const float* p1 = w_hh + (long)rowN1 * Hn + koff;
        bf16x8 b0, b1;
        #pragma unroll
        for (int j = 0; j < 8; ++j) {
            b0[j] = (short)f2b(p0[j]);
            b1[j] = (short)f2b(p1[j]);
        }
        Bf0[k] = b0;
        Bf1[k] = b1;
    }

    // Epilogue constants (used by waves 0-3, lanes n16<8)
    float wr0 = w_ih[jg*3+0], wr1 = w_ih[jg*3+1], wr2 = w_ih[jg*3+2];
    float wz0 = w_ih[(Hn+jg)*3+0], wz1 = w_ih[(Hn+jg)*3+1], wz2 = w_ih[(Hn+jg)*3+2];
    float wn0 = w_ih[(2*Hn+jg)*3+0], wn1 = w_ih[(2*Hn+jg)*3+1], wn2 = w_ih[(2*Hn+jg)*3+2];
    float br_ = bias[jg], bz_ = bias[Hn+jg], bn2_ = bias[2*Hn+jg];
    float bnn_ = bias_n[jg];

    // fp32 hidden state registers (waves 0-3; batch b = 16*mt_own + quad*4 + r)
    float hst[4];
    #pragma unroll
    for (int r = 0; r < 4; ++r)
        hst[r] = init_h[(long)(16 * mt_own + quad * 4 + r) * Hn + jg];

    // Epilogue frag-store constants: j = 8*bid + jj
    const int kkE = blockIdx.x >> 2;   // j>>5
    const int qE  = blockIdx.x & 3;    // (j>>3)&3

    for (int t = 0; t < Tn; ++t) {
        const unsigned short* hcur = (t & 1) ? h1 : h0;
        unsigned short* hnext      = (t & 1) ? h0 : h1;

        // input contributions for this step (overlaps with k-loop)
        float xv[4][3];
        if (w < 4) {
            #pragma unroll
            for (int r = 0; r < 4; ++r) {
                const float* xp = inp + ((long)t * Bn + 16 * w + quad * 4 + r) * 3;
                xv[r][0] = xp[0]; xv[r][1] = xp[1]; xv[r][2] = xp[2];
            }
        }

        f32x4 acc[4][2];
        #pragma unroll
        for (int mt = 0; mt < 4; ++mt) {
            acc[mt][0] = f32x4{0.f, 0.f, 0.f, 0.f};
            acc[mt][1] = f32x4{0.f, 0.f, 0.f, 0.f};
        }

        #pragma unroll 2
        for (int k = 0; k < 8; ++k) {
            #pragma unroll
            for (int mt = 0; mt < 4; ++mt) {
                // coalesced frag-layout A load: 64 lanes x 16B contiguous (cached;
                // XCD L2 shares the h broadcast across its 32 CUs)
                bf16x8 a = *(const bf16x8*)(hcur + ((((w * 8 + k) * 4 + mt) * 64) + lane) * 8);
                acc[mt][0] = __builtin_amdgcn_mfma_f32_16x16x32_bf16(a, Bf0[k], acc[mt][0], 0, 0, 0);
                acc[mt][1] = __builtin_amdgcn_mfma_f32_16x16x32_bf16(a, Bf1[k], acc[mt][1], 0, 0, 0);
            }
        }

        // dump partials to LDS
        #pragma unroll
        for (int mt = 0; mt < 4; ++mt) {
            red[((w * 4 + mt) * 2 + 0) * 64 + lane] = acc[mt][0];
            red[((w * 4 + mt) * 2 + 1) * 64 + lane] = acc[mt][1];
        }
        __syncthreads();

        if (w < 4) {
            // reduce over the 8 K-slices for M-tile mt_own
            f32x4 s0 = red[((0 * 4 + mt_own) * 2 + 0) * 64 + lane];
            f32x4 s1 = red[((0 * 4 + mt_own) * 2 + 1) * 64 + lane];
            #pragma unroll
            for (int ww = 1; ww < 8; ++ww) {
                s0 += red[((ww * 4 + mt_own) * 2 + 0) * 64 + lane];
                s1 += red[((ww * 4 + mt_own) * 2 + 1) * 64 + lane];
            }
            #pragma unroll
            for (int r = 0; r < 4; ++r) {
                float rdot = s0[r];
                float ndot = s1[r];
                float zdot = __shfl_xor(rdot, 8, 64);  // all lanes execute
                if (n16 < 8) {
                    const int b = 16 * mt_own + quad * 4 + r;
                    float pr = br_ + wr0*xv[r][0] + wr1*xv[r][1] + wr2*xv[r][2] + rdot;
                    float pz = bz_ + wz0*xv[r][0] + wz1*xv[r][1] + wz2*xv[r][2] + zdot;
                    float rr = sigm(pr);
                    float zz = sigm(pz);
                    float pn = bn2_ + wn0*xv[r][0] + wn1*xv[r][1] + wn2*xv[r][2] + rr * (ndot + bnn_);
                    float nn = tanh_f(pn);
                    float hv = nn + zz * (hst[r] - nn);
                    hst[r] = hv;
                    // frag-layout write-through store (MALL-visible at vmcnt retire)
                    store_short_wt(hnext + ((long)((kkE * 4 + mt_own) * 64) + qE * 16 + quad * 4 + r) * 8 + jj,
                                   (unsigned)f2b(hv));
                    if (blockIdx.x == 0 && n16 == 0)
                        store_dword_wt(out + t * Bn + b, hv);
                }
            }
        }

        // ---- grid barrier (NO fences; see protocol comment above) ----
        __syncthreads();   // drains vmcnt(0) per wave -> all WT stores at MALL
        if (tid == 0) {
            unsigned old = __hip_atomic_fetch_add(&ctrl[(blockIdx.x >> 3) * LEAF_STRIDE], 1u,
                                                  __ATOMIC_RELAXED, __HIP_MEMORY_SCOPE_AGENT);
            if ((old & 7) == 7) {
                unsigned old2 = __hip_atomic_fetch_add(&ctrl[ROOT_IDX], 1u,
                                                       __ATOMIC_RELAXED, __HIP_MEMORY_SCOPE_AGENT);
                if ((old2 & 31) == 31) {
                    __hip_atomic_fetch_add(&ctrl[FLAG_IDX], 1u,
                                           __ATOMIC_RELAXED, __HIP_MEMORY_SCOPE_AGENT);
                }
            }
            const unsigned* fp = &ctrl[FLAG_IDX];
            const unsigned tgt = (unsigned)(t + 1);
            for (;;) {
                unsigned v;
                // cache-BYPASS load (sc0 sc1): fresh from MALL, no buffer_inv
                asm volatile("global_load_dword %0, %1, off sc0 sc1\n\t"
                             "s_waitcnt vmcnt(0)"
                             : "=v"(v) : "v"(fp) : "memory");
                if (v >= tgt) break;
                __builtin_amdgcn_s_sleep(2);
            }
            // acquire: ONE invalidate per block per step (drops stale h lines;
            // all dirty-shared data is write-through so nothing is lost)
            asm volatile("buffer_inv sc1\n\ts_waitcnt vmcnt(0)" ::: "memory");
        }
        __syncthreads();
    }
}

extern "C" void kernel_launch(void* const* d_in, const int* in_sizes, int n_in,
                              void* d_out, int out_size, void* d_ws, size_t ws_size,
                              hipStream_t stream) {
    const float* inp    = (const float*)d_in[0];  // [1024][64][3]
    const float* init_h = (const float*)d_in[1];  // [64][2048]
    const float* w_ih   = (const float*)d_in[2];  // [6144][3]
    const float* w_hh   = (const float*)d_in[3];  // [6144][2048]
    const float* bias   = (const float*)d_in[4];  // [6144]
    const float* bias_n = (const float*)d_in[5];  // [2048]
    float* out = (float*)d_out;                   // [1024][64]

    unsigned short* h0 = (unsigned short*)d_ws;          // 262144 B
    unsigned short* h1 = h0 + 131072L;                   // 262144 B
    unsigned* ctrl     = (unsigned*)(h1 + 131072L);      // 8192 B

    prep_kernel<<<128, 256, 0, stream>>>(init_h, h0, ctrl);
    gru_kernel<<<NBLK, NTHR, 0, stream>>>(inp, init_h, w_ih, w_hh, bias, bias_n,
                                          h0, h1, ctrl, out);
}

// Round 6
// 13014.973 us; speedup vs baseline: 11.8763x; 7.6566x over previous
//
#include <hip/hip_runtime.h>

typedef __attribute__((ext_vector_type(8))) short bf16x8;
typedef __attribute__((ext_vector_type(4))) float f32x4;

#define Tn 1024
#define Bn 64
#define Hn 2048
#define NBLK 128
#define NTHR 512

// ctrl word indices (each on its own 128B line)
#define LEAF_CTR(i)  ((i) * 32)
#define ROOT_CTR     (16 * 32)
#define ROOT_FLAG    (17 * 32)
#define LEAF_FLAG(i) ((18 + (i)) * 32)

__device__ __forceinline__ unsigned short f2b(float x) {
    // fp32 -> bf16 round-to-nearest-even
    unsigned u = __float_as_uint(x);
    return (unsigned short)((u + 0x7fffu + ((u >> 16) & 1u)) >> 16);
}
__device__ __forceinline__ float sigm(float x) {
    return __builtin_amdgcn_rcpf(1.0f + __expf(-x));
}
__device__ __forceinline__ float tanh_f(float x) {
    float e = __expf(2.0f * x);
    return 1.0f - 2.0f * __builtin_amdgcn_rcpf(1.0f + e);
}

// write-through system-scope stores: at MALL once vmcnt retires
__device__ __forceinline__ void store_short_wt(unsigned short* p, unsigned v) {
    asm volatile("global_store_short %0, %1, off sc0 sc1" :: "v"(p), "v"(v) : "memory");
}
__device__ __forceinline__ void store_dword_wt(float* p, float v) {
    asm volatile("global_store_dword %0, %1, off sc0 sc1" :: "v"(p), "v"(__float_as_uint(v)) : "memory");
}
__device__ __forceinline__ void store_u64_wt(unsigned long long* p, unsigned long long v) {
    asm volatile("global_store_dwordx2 %0, %1, off sc0 sc1" :: "v"(p), "v"(v) : "memory");
}
// Poll via atomic RMW(+0): the ONLY read primitive proven coherent cross-XCD
// (R1-R5: every load flavor — cached, relaxed, sc0/sc1 bypass — showed
// ~100us eviction-timescale staleness; RMWs never lost a count).
// asm because InstCombine turns fetch_add(p,0) back into a plain atomic load.
__device__ __forceinline__ unsigned poll_read(unsigned* p) {
    unsigned old;
    asm volatile("global_atomic_add %0, %1, %2, off sc0 sc1\n\ts_waitcnt vmcnt(0)"
                 : "=v"(old) : "v"(p), "v"(0u) : "memory");
    return old;
}
// fresh h read: relaxed system-scope atomic load = global_load_dwordx2 sc0 sc1
// (bypasses L1/L2 -> reads MALL where the WT stores land; compiler-tracked
// vmcnt so loads pipeline normally)
__device__ __forceinline__ bf16x8 load_h_frag(const unsigned short* p) {
    unsigned long long lo = __hip_atomic_load((const unsigned long long*)p,
                                              __ATOMIC_RELAXED, __HIP_MEMORY_SCOPE_SYSTEM);
    unsigned long long hi = __hip_atomic_load((const unsigned long long*)(p + 4),
                                              __ATOMIC_RELAXED, __HIP_MEMORY_SCOPE_SYSTEM);
    union { unsigned long long q[2]; bf16x8 v; } u;
    u.q[0] = lo; u.q[1] = hi;
    return u.v;
}

// h fragment layout: h_f[kk][mt][laneF][e], kk=k>>5, mt=b>>4,
// laneF=((k>>3)&3)*16+(b&15), e=k&7. One MFMA A-frag = 64 lanes x 16B contig.
__device__ __forceinline__ long hfrag_off(int b, int k) {
    return ((long)(((k >> 5) * 4 + (b >> 4)) * 64) + ((k >> 3) & 3) * 16 + (b & 15)) * 8 + (k & 7);
}

// Prep: init_hidden fp32 -> bf16 h0 (frag layout, WT stores so the MALL copy
// is authoritative for gru's bypass loads); zero barrier ctrl (WT too).
__global__ void prep_kernel(const float* __restrict__ init_h,
                            unsigned short* __restrict__ h0,
                            unsigned* __restrict__ ctrl) {
    const int i = blockIdx.x * 256 + threadIdx.x;  // 0..32767
    const int b  = i >> 9;
    const int k4 = (i & 511) << 2;
    float4 v = *reinterpret_cast<const float4*>(init_h + (long)b * Hn + k4);
    unsigned long long q = (unsigned long long)f2b(v.x)
                         | ((unsigned long long)f2b(v.y) << 16)
                         | ((unsigned long long)f2b(v.z) << 32)
                         | ((unsigned long long)f2b(v.w) << 48);
    store_u64_wt((unsigned long long*)(h0 + hfrag_off(b, k4)), q);
    if (i < 2048)
        asm volatile("global_store_dword %0, %1, off sc0 sc1"
                     :: "v"(ctrl + i), "v"(0u) : "memory");
}

// Persistent GRU. 128 blocks x 512 threads (8 waves).
// Block bk owns 16 hidden units j in [16*bk, 16*bk+16).
// Wave w owns K-slice [256w, 256w+256); W rows live in REGISTERS (Bf[3][8]):
//   N-tile0=r rows, tile1=z rows, tile2=n rows (16 cols each, zero padding).
// Per wave per step: 8 k-iters x 4 M-tiles x 3 N-tiles MFMA 16x16x32_bf16.
// Two-round LDS reduction (48KB); wave m<4 epilogues M-tile m, all 64 lanes.
// fp32 hidden state in registers at MFMA C-layout positions.
// NO fences / NO buffer_inv / NO wbl2 anywhere in the hot loop.
__global__ void __launch_bounds__(NTHR, 2) gru_kernel(
    const float* __restrict__ inp,     // [T][B][3]
    const float* __restrict__ init_h,  // [B][H]
    const float* __restrict__ w_ih,    // [3H][3]
    const float* __restrict__ w_hh,    // [3H][H] fp32
    const float* __restrict__ bias,    // [3H]
    const float* __restrict__ bias_n,  // [H]
    unsigned short* __restrict__ h0,   // [B][H] bf16 frag-layout double buffer
    unsigned short* __restrict__ h1,
    unsigned* __restrict__ ctrl,       // [2048] barrier counters + flags
    float* __restrict__ out)           // [T][B]
{
    __shared__ f32x4 red[4][4][3][64];  // [src][mt][nt][lane] = 48 KB

    const int tid  = threadIdx.x;
    const int lane = tid & 63;
    const int w    = tid >> 6;      // wave id = K-slice owner
    const int quad = lane >> 4;
    const int n16  = lane & 15;
    const int j0   = blockIdx.x * 16;
    const int jg   = j0 + n16;      // this lane's hidden column (epilogue)
    const int ks   = w * 256;

    // ---- preload W rows into registers as bf16 B-fragments (one-time) ----
    bf16x8 Bf[3][8];
    #pragma unroll
    for (int nt = 0; nt < 3; ++nt) {
        const long row = (long)(nt * Hn + j0 + n16);
        #pragma unroll
        for (int k = 0; k < 8; ++k) {
            const float* p = w_hh + row * Hn + ks + k * 32 + quad * 8;
            bf16x8 b;
            #pragma unroll
            for (int j = 0; j < 8; ++j) b[j] = (short)f2b(p[j]);
            Bf[nt][k] = b;
        }
    }

    // Epilogue constants (used by waves 0-3; all 64 lanes active)
    float wr0 = w_ih[jg*3+0], wr1 = w_ih[jg*3+1], wr2 = w_ih[jg*3+2];
    float wz0 = w_ih[(Hn+jg)*3+0], wz1 = w_ih[(Hn+jg)*3+1], wz2 = w_ih[(Hn+jg)*3+2];
    float wn0 = w_ih[(2*Hn+jg)*3+0], wn1 = w_ih[(2*Hn+jg)*3+1], wn2 = w_ih[(2*Hn+jg)*3+2];
    float br_ = bias[jg], bz_ = bias[Hn+jg], bn2_ = bias[2*Hn+jg];
    float bnn_ = bias_n[jg];

    // fp32 hidden state (waves 0-3; batch b = 16*w + quad*4 + r, col jg)
    float hst[4];
    if (w < 4) {
        #pragma unroll
        for (int r = 0; r < 4; ++r)
            hst[r] = init_h[(long)(16 * w + quad * 4 + r) * Hn + jg];
    }

    // epilogue frag-store decomposition of j = 16*bid + n16
    const int kkE = blockIdx.x >> 1;            // j>>5 (lane-uniform)
    const int qE  = (blockIdx.x & 1) * 2 + (n16 >> 3);
    const int eE  = n16 & 7;

    const int leaf = blockIdx.x >> 3;           // 16 leaves x 8 blocks

    for (int t = 0; t < Tn; ++t) {
        const unsigned short* hcur = (t & 1) ? h1 : h0;
        unsigned short* hnext      = (t & 1) ? h0 : h1;

        // input contributions for this step (cached loads; inp is read-only)
        float xv[4][3];
        if (w < 4) {
            #pragma unroll
            for (int r = 0; r < 4; ++r) {
                const float* xp = inp + ((long)t * Bn + 16 * w + quad * 4 + r) * 3;
                xv[r][0] = xp[0]; xv[r][1] = xp[1]; xv[r][2] = xp[2];
            }
        }

        f32x4 acc[4][3];
        #pragma unroll
        for (int mt = 0; mt < 4; ++mt)
            #pragma unroll
            for (int nt = 0; nt < 3; ++nt)
                acc[mt][nt] = f32x4{0.f, 0.f, 0.f, 0.f};

        const unsigned short* pa = hcur + (long)(w * 8 * 4 * 64 + lane) * 8;
        #pragma unroll 2
        for (int k = 0; k < 8; ++k) {
            #pragma unroll
            for (int mt = 0; mt < 4; ++mt) {
                bf16x8 a = load_h_frag(pa + (long)(k * 4 + mt) * 64 * 8);
                acc[mt][0] = __builtin_amdgcn_mfma_f32_16x16x32_bf16(a, Bf[0][k], acc[mt][0], 0, 0, 0);
                acc[mt][1] = __builtin_amdgcn_mfma_f32_16x16x32_bf16(a, Bf[1][k], acc[mt][1], 0, 0, 0);
                acc[mt][2] = __builtin_amdgcn_mfma_f32_16x16x32_bf16(a, Bf[2][k], acc[mt][2], 0, 0, 0);
            }
        }

        // ---- two-round cross-wave K reduction through LDS ----
        if (w >= 4) {
            #pragma unroll
            for (int mt = 0; mt < 4; ++mt)
                #pragma unroll
                for (int nt = 0; nt < 3; ++nt)
                    red[w - 4][mt][nt][lane] = acc[mt][nt];
        }
        __syncthreads();
        if (w < 4) {
            #pragma unroll
            for (int mt = 0; mt < 4; ++mt)
                #pragma unroll
                for (int nt = 0; nt < 3; ++nt)
                    acc[mt][nt] += red[w][mt][nt][lane];
        }
        __syncthreads();
        if (w < 4) {
            #pragma unroll
            for (int mt = 0; mt < 4; ++mt)
                #pragma unroll
                for (int nt = 0; nt < 3; ++nt)
                    red[w][mt][nt][lane] = acc[mt][nt];
        }
        __syncthreads();

        if (w < 4) {
            f32x4 s0 = red[0][w][0][lane], s1 = red[0][w][1][lane], s2 = red[0][w][2][lane];
            #pragma unroll
            for (int src = 1; src < 4; ++src) {
                s0 += red[src][w][0][lane];
                s1 += red[src][w][1][lane];
                s2 += red[src][w][2][lane];
            }
            #pragma unroll
            for (int r = 0; r < 4; ++r) {
                const int b = 16 * w + quad * 4 + r;
                float pr = br_ + wr0*xv[r][0] + wr1*xv[r][1] + wr2*xv[r][2] + s0[r];
                float pz = bz_ + wz0*xv[r][0] + wz1*xv[r][1] + wz2*xv[r][2] + s1[r];
                float rr = sigm(pr);
                float zz = sigm(pz);
                float pn = bn2_ + wn0*xv[r][0] + wn1*xv[r][1] + wn2*xv[r][2] + rr * (s2[r] + bnn_);
                float nn = tanh_f(pn);
                float hv = nn + zz * (hst[r] - nn);
                hst[r] = hv;
                store_short_wt(hnext + ((long)((kkE * 4 + w) * 64) + qE * 16 + quad * 4 + r) * 8 + eE,
                               (unsigned)f2b(hv));
                if (blockIdx.x == 0 && n16 == 0)
                    store_dword_wt(out + t * Bn + b, hv);
            }
        }

        // ---- grid barrier: all signals via RMW, all polls via RMW(+0) ----
        __syncthreads();   // compiler drains vmcnt(0) -> WT stores at MALL
        if (tid == 0) {
            const unsigned tgt = (unsigned)(t + 1);
            unsigned old = __hip_atomic_fetch_add(&ctrl[LEAF_CTR(leaf)], 1u,
                                                  __ATOMIC_RELAXED, __HIP_MEMORY_SCOPE_SYSTEM);
            if ((old & 7) == 7) {      // this block closed its leaf
                unsigned o2 = __hip_atomic_fetch_add(&ctrl[ROOT_CTR], 1u,
                                                     __ATOMIC_RELAXED, __HIP_MEMORY_SCOPE_SYSTEM);
                if ((o2 & 15) == 15)   // closed the root: release step t
                    __hip_atomic_fetch_add(&ctrl[ROOT_FLAG], 1u,
                                           __ATOMIC_RELAXED, __HIP_MEMORY_SCOPE_SYSTEM);
                while (poll_read(&ctrl[ROOT_FLAG]) < tgt)
                    __builtin_amdgcn_s_sleep(2);
                __hip_atomic_fetch_add(&ctrl[LEAF_FLAG(leaf)], 1u,
                                       __ATOMIC_RELAXED, __HIP_MEMORY_SCOPE_SYSTEM);
            } else {
                while (poll_read(&ctrl[LEAF_FLAG(leaf)]) < tgt)
                    __builtin_amdgcn_s_sleep(2);
            }
        }
        __syncthreads();
    }
}

extern "C" void kernel_launch(void* const* d_in, const int* in_sizes, int n_in,
                              void* d_out, int out_size, void* d_ws, size_t ws_size,
                              hipStream_t stream) {
    const float* inp    = (const float*)d_in[0];  // [1024][64][3]
    const float* init_h = (const float*)d_in[1];  // [64][2048]
    const float* w_ih   = (const float*)d_in[2];  // [6144][3]
    const float* w_hh   = (const float*)d_in[3];  // [6144][2048]
    const float* bias   = (const float*)d_in[4];  // [6144]
    const float* bias_n = (const float*)d_in[5];  // [2048]
    float* out = (float*)d_out;                   // [1024][64]

    unsigned short* h0 = (unsigned short*)d_ws;          // 262144 B
    unsigned short* h1 = h0 + 131072L;                   // 262144 B
    unsigned* ctrl     = (unsigned*)(h1 + 131072L);      // 8192 B

    prep_kernel<<<128, 256, 0, stream>>>(init_h, h0, ctrl);
    gru_kernel<<<NBLK, NTHR, 0, stream>>>(inp, init_h, w_ih, w_hh, bias, bias_n,
                                          h0, h1, ctrl, out);
}

// Round 9
// 12655.225 us; speedup vs baseline: 12.2139x; 1.0284x over previous
//
#include <hip/hip_runtime.h>

typedef __attribute__((ext_vector_type(8))) short bf16x8;
typedef __attribute__((ext_vector_type(4))) float f32x4;

#define Tn 1024
#define Bn 64
#define Hn 2048
#define NBLK 128
#define NTHR 512

// ctrl word indices (each on its own 128B line)
#define LEAF_CTR(i)  ((i) * 32)
#define ROOT_CTR     (16 * 32)
#define LEAF_FLAG(i) ((18 + (i)) * 32)

// watchdog: bounded spin so a liveness bug degrades to a wrong answer
// (diagnosable absmax failure) instead of a container-killing hang
#define SPIN_LIMIT (1u << 25)

__device__ __forceinline__ unsigned short f2b(float x) {
    // fp32 -> bf16 round-to-nearest-even
    unsigned u = __float_as_uint(x);
    return (unsigned short)((u + 0x7fffu + ((u >> 16) & 1u)) >> 16);
}
__device__ __forceinline__ float sigm(float x) {
    return __builtin_amdgcn_rcpf(1.0f + __expf(-x));
}
__device__ __forceinline__ float tanh_f(float x) {
    float e = __expf(2.0f * x);
    return 1.0f - 2.0f * __builtin_amdgcn_rcpf(1.0f + e);
}

// write-through system-scope stores: at MALL once vmcnt retires
__device__ __forceinline__ void store_short_wt(unsigned short* p, unsigned v) {
    asm volatile("global_store_short %0, %1, off sc0 sc1" :: "v"(p), "v"(v) : "memory");
}
__device__ __forceinline__ void store_dword_wt(float* p, float v) {
    asm volatile("global_store_dword %0, %1, off sc0 sc1" :: "v"(p), "v"(__float_as_uint(v)) : "memory");
}
__device__ __forceinline__ void store_u64_wt(unsigned long long* p, unsigned long long v) {
    asm volatile("global_store_dwordx2 %0, %1, off sc0 sc1" :: "v"(p), "v"(v) : "memory");
}
// Poll via atomic RMW(+0): the ONLY read primitive proven promptly coherent
// cross-XCD for atomically-updated lines (R1-R6 ablation). asm because
// InstCombine turns fetch_add(p,0) back into a plain atomic load.
__device__ __forceinline__ unsigned poll_read(unsigned* p) {
    unsigned old;
    asm volatile("global_atomic_add %0, %1, %2, off sc0 sc1\n\ts_waitcnt vmcnt(0)"
                 : "=v"(old) : "v"(p), "v"(0u) : "memory");
    return old;
}
// fresh h read: relaxed system-scope atomic load = global_load_dwordx2 sc0 sc1
// (bypasses L1/L2 -> reads MALL where WT stores land; compiler-tracked vmcnt
// so loads pipeline). WT-store -> bypass-load proven coherent in R6.
__device__ __forceinline__ bf16x8 load_h_frag(const unsigned short* p) {
    unsigned long long lo = __hip_atomic_load((const unsigned long long*)p,
                                              __ATOMIC_RELAXED, __HIP_MEMORY_SCOPE_SYSTEM);
    unsigned long long hi = __hip_atomic_load((const unsigned long long*)(p + 4),
                                              __ATOMIC_RELAXED, __HIP_MEMORY_SCOPE_SYSTEM);
    union { unsigned long long q[2]; bf16x8 v; } u;
    u.q[0] = lo; u.q[1] = hi;
    return u.v;
}

// h fragment layout: h_f[kk][mt][laneF][e], kk=k>>5, mt=b>>4,
// laneF=((k>>3)&3)*16+(b&15), e=k&7. One MFMA A-frag = 64 lanes x 16B contig.
__device__ __forceinline__ long hfrag_off(int b, int k) {
    return ((long)(((k >> 5) * 4 + (b >> 4)) * 64) + ((k >> 3) & 3) * 16 + (b & 15)) * 8 + (k & 7);
}

// Prep: init_hidden fp32 -> bf16 h0 (frag layout, WT stores so the MALL copy
// is authoritative for gru's bypass loads); zero barrier ctrl (WT too).
__global__ void prep_kernel(const float* __restrict__ init_h,
                            unsigned short* __restrict__ h0,
                            unsigned* __restrict__ ctrl) {
    const int i = blockIdx.x * 256 + threadIdx.x;  // 0..32767
    const int b  = i >> 9;
    const int k4 = (i & 511) << 2;
    float4 v = *reinterpret_cast<const float4*>(init_h + (long)b * Hn + k4);
    unsigned long long q = (unsigned long long)f2b(v.x)
                         | ((unsigned long long)f2b(v.y) << 16)
                         | ((unsigned long long)f2b(v.z) << 32)
                         | ((unsigned long long)f2b(v.w) << 48);
    store_u64_wt((unsigned long long*)(h0 + hfrag_off(b, k4)), q);
    if (i < 2048)
        asm volatile("global_store_dword %0, %1, off sc0 sc1"
                     :: "v"(ctrl + i), "v"(0u) : "memory");
}

// Persistent GRU. 128 blocks x 512 threads (8 waves).
// Block bk owns 16 hidden units j in [16*bk, 16*bk+16).
// Wave w owns K-slice [256w, 256w+256); W rows live in REGISTERS (Bf[3][8]):
//   N-tile0=r rows, tile1=z rows, tile2=n rows (16 cols each, no padding).
// Per wave per step: 8 k-iters x 4 M-tiles x 3 N-tiles MFMA 16x16x32_bf16.
// TWO-ROUND LDS reduction (48 KB — 96 KB static LDS killed the container in
// R7/R8, apparently a >64 KB static-LDS launch failure; do NOT raise this).
// fp32 hidden state in registers at MFMA C-layout positions.
// NO fences / NO cache maintenance anywhere in the hot loop (R5 lesson).
// Barrier: leaf arrive RMW -> (closer) root arrive RMW -> closers poll root
// counter directly (no root-flag hop) -> leaf flag RMW -> members poll.
__global__ void __launch_bounds__(NTHR, 2) gru_kernel(
    const float* __restrict__ inp,     // [T][B][3]
    const float* __restrict__ init_h,  // [B][H]
    const float* __restrict__ w_ih,    // [3H][3]
    const float* __restrict__ w_hh,    // [3H][H] fp32
    const float* __restrict__ bias,    // [3H]
    const float* __restrict__ bias_n,  // [H]
    unsigned short* __restrict__ h0,   // [B][H] bf16 frag-layout double buffer
    unsigned short* __restrict__ h1,
    unsigned* __restrict__ ctrl,       // [2048] barrier counters + flags
    float* __restrict__ out)           // [T][B]
{
    __shared__ f32x4 red[4][4][3][64];  // [src][mt][nt][lane] = 48 KB

    const int tid  = threadIdx.x;
    const int lane = tid & 63;
    const int w    = tid >> 6;      // wave id = K-slice owner
    const int quad = lane >> 4;
    const int n16  = lane & 15;
    const int j0   = blockIdx.x * 16;
    const int jg   = j0 + n16;      // this lane's hidden column (epilogue)
    const int ks   = w * 256;

    // ---- preload W rows into registers as bf16 B-fragments (one-time) ----
    bf16x8 Bf[3][8];
    #pragma unroll
    for (int nt = 0; nt < 3; ++nt) {
        const long row = (long)(nt * Hn + j0 + n16);
        #pragma unroll
        for (int k = 0; k < 8; ++k) {
            const float* p = w_hh + row * Hn + ks + k * 32 + quad * 8;
            bf16x8 b;
            #pragma unroll
            for (int j = 0; j < 8; ++j) b[j] = (short)f2b(p[j]);
            Bf[nt][k] = b;
        }
    }

    // Epilogue constants (used by waves 0-3; all 64 lanes active)
    float wr0 = w_ih[jg*3+0], wr1 = w_ih[jg*3+1], wr2 = w_ih[jg*3+2];
    float wz0 = w_ih[(Hn+jg)*3+0], wz1 = w_ih[(Hn+jg)*3+1], wz2 = w_ih[(Hn+jg)*3+2];
    float wn0 = w_ih[(2*Hn+jg)*3+0], wn1 = w_ih[(2*Hn+jg)*3+1], wn2 = w_ih[(2*Hn+jg)*3+2];
    float br_ = bias[jg], bz_ = bias[Hn+jg], bn2_ = bias[2*Hn+jg];
    float bnn_ = bias_n[jg];

    // fp32 hidden state (waves 0-3; batch b = 16*w + quad*4 + r, col jg)
    float hst[4];
    if (w < 4) {
        #pragma unroll
        for (int r = 0; r < 4; ++r)
            hst[r] = init_h[(long)(16 * w + quad * 4 + r) * Hn + jg];
    }

    // epilogue frag-store decomposition of j = 16*bid + n16
    const int kkE = blockIdx.x >> 1;            // j>>5 (lane-uniform)
    const int qE  = (blockIdx.x & 1) * 2 + (n16 >> 3);
    const int eE  = n16 & 7;

    const int leaf = blockIdx.x >> 3;           // 16 leaves x 8 blocks

    for (int t = 0; t < Tn; ++t) {
        const unsigned short* hcur = (t & 1) ? h1 : h0;
        unsigned short* hnext      = (t & 1) ? h0 : h1;

        // input contributions for this step (cached loads; inp is read-only)
        float xv[4][3];
        if (w < 4) {
            #pragma unroll
            for (int r = 0; r < 4; ++r) {
                const float* xp = inp + ((long)t * Bn + 16 * w + quad * 4 + r) * 3;
                xv[r][0] = xp[0]; xv[r][1] = xp[1]; xv[r][2] = xp[2];
            }
        }

        f32x4 acc[4][3];
        #pragma unroll
        for (int mt = 0; mt < 4; ++mt)
            #pragma unroll
            for (int nt = 0; nt < 3; ++nt)
                acc[mt][nt] = f32x4{0.f, 0.f, 0.f, 0.f};

        const unsigned short* pa = hcur + (long)(w * 8 * 4 * 64 + lane) * 8;
        #pragma unroll 2
        for (int k = 0; k < 8; ++k) {
            #pragma unroll
            for (int mt = 0; mt < 4; ++mt) {
                bf16x8 a = load_h_frag(pa + (long)(k * 4 + mt) * 64 * 8);
                acc[mt][0] = __builtin_amdgcn_mfma_f32_16x16x32_bf16(a, Bf[0][k], acc[mt][0], 0, 0, 0);
                acc[mt][1] = __builtin_amdgcn_mfma_f32_16x16x32_bf16(a, Bf[1][k], acc[mt][1], 0, 0, 0);
                acc[mt][2] = __builtin_amdgcn_mfma_f32_16x16x32_bf16(a, Bf[2][k], acc[mt][2], 0, 0, 0);
            }
        }

        // ---- two-round cross-wave K reduction through LDS (48 KB) ----
        if (w >= 4) {
            #pragma unroll
            for (int mt = 0; mt < 4; ++mt)
                #pragma unroll
                for (int nt = 0; nt < 3; ++nt)
                    red[w - 4][mt][nt][lane] = acc[mt][nt];
        }
        __syncthreads();
        if (w < 4) {
            #pragma unroll
            for (int mt = 0; mt < 4; ++mt)
                #pragma unroll
                for (int nt = 0; nt < 3; ++nt)
                    acc[mt][nt] += red[w][mt][nt][lane];
        }
        __syncthreads();
        if (w < 4) {
            #pragma unroll
            for (int mt = 0; mt < 4; ++mt)
                #pragma unroll
                for (int nt = 0; nt < 3; ++nt)
                    red[w][mt][nt][lane] = acc[mt][nt];
        }
        __syncthreads();

        if (w < 4) {
            f32x4 s0 = red[0][w][0][lane], s1 = red[0][w][1][lane], s2 = red[0][w][2][lane];
            #pragma unroll
            for (int src = 1; src < 4; ++src) {
                s0 += red[src][w][0][lane];
                s1 += red[src][w][1][lane];
                s2 += red[src][w][2][lane];
            }
            #pragma unroll
            for (int r = 0; r < 4; ++r) {
                const int b = 16 * w + quad * 4 + r;
                float pr = br_ + wr0*xv[r][0] + wr1*xv[r][1] + wr2*xv[r][2] + s0[r];
                float pz = bz_ + wz0*xv[r][0] + wz1*xv[r][1] + wz2*xv[r][2] + s1[r];
                float rr = sigm(pr);
                float zz = sigm(pz);
                float pn = bn2_ + wn0*xv[r][0] + wn1*xv[r][1] + wn2*xv[r][2] + rr * (s2[r] + bnn_);
                float nn = tanh_f(pn);
                float hv = nn + zz * (hst[r] - nn);
                hst[r] = hv;
                store_short_wt(hnext + ((long)((kkE * 4 + w) * 64) + qE * 16 + quad * 4 + r) * 8 + eE,
                               (unsigned)f2b(hv));
                if (blockIdx.x == 0 && n16 == 0)
                    store_dword_wt(out + t * Bn + b, hv);
            }
        }

        // ---- grid barrier: all signals via RMW, all polls via RMW(+0) ----
        __syncthreads();   // drains vmcnt(0) per wave -> WT stores at MALL
        if (tid == 0) {
            const unsigned tgt = (unsigned)(t + 1);
            unsigned old = __hip_atomic_fetch_add(&ctrl[LEAF_CTR(leaf)], 1u,
                                                  __ATOMIC_RELAXED, __HIP_MEMORY_SCOPE_SYSTEM);
            unsigned spins = 0;
            if ((old & 7) == 7) {      // this block closed its leaf
                __hip_atomic_fetch_add(&ctrl[ROOT_CTR], 1u,
                                       __ATOMIC_RELAXED, __HIP_MEMORY_SCOPE_SYSTEM);
                // poll the root COUNTER directly (no flag hop): 16 pollers
                while (poll_read(&ctrl[ROOT_CTR]) < 16u * tgt) {
                    __builtin_amdgcn_s_sleep(1);
                    if (++spins > SPIN_LIMIT) break;   // watchdog
                }
                __hip_atomic_fetch_add(&ctrl[LEAF_FLAG(leaf)], 1u,
                                       __ATOMIC_RELAXED, __HIP_MEMORY_SCOPE_SYSTEM);
            } else {
                while (poll_read(&ctrl[LEAF_FLAG(leaf)]) < tgt) {
                    __builtin_amdgcn_s_sleep(1);
                    if (++spins > SPIN_LIMIT) break;   // watchdog
                }
            }
        }
        __syncthreads();
    }
}

extern "C" void kernel_launch(void* const* d_in, const int* in_sizes, int n_in,
                              void* d_out, int out_size, void* d_ws, size_t ws_size,
                              hipStream_t stream) {
    const float* inp    = (const float*)d_in[0];  // [1024][64][3]
    const float* init_h = (const float*)d_in[1];  // [64][2048]
    const float* w_ih   = (const float*)d_in[2];  // [6144][3]
    const float* w_hh   = (const float*)d_in[3];  // [6144][2048]
    const float* bias   = (const float*)d_in[4];  // [6144]
    const float* bias_n = (const float*)d_in[5];  // [2048]
    float* out = (float*)d_out;                   // [1024][64]

    unsigned short* h0 = (unsigned short*)d_ws;          // 262144 B
    unsigned short* h1 = h0 + 131072L;                   // 262144 B
    unsigned* ctrl     = (unsigned*)(h1 + 131072L);      // 8192 B

    prep_kernel<<<128, 256, 0, stream>>>(init_h, h0, ctrl);
    gru_kernel<<<NBLK, NTHR, 0, stream>>>(inp, init_h, w_ih, w_hh, bias, bias_n,
                                          h0, h1, ctrl, out);
}

// Round 11
// 8258.288 us; speedup vs baseline: 18.7169x; 1.5324x over previous
//
#include <hip/hip_runtime.h>

typedef __attribute__((ext_vector_type(8))) short bf16x8;
typedef __attribute__((ext_vector_type(4))) float f32x4;

#define Tn 1024
#define Bn 64
#define Hn 2048
#define NBLK 128
#define NTHR 512

// ctrl word indices (each on its own 128B line)
#define LEAF_CTR(i)  ((i) * 32)
#define ROOT_CTR     (16 * 32)
#define LEAF_FLAG(i) ((18 + (i)) * 32)

// watchdog: bounded spin so a liveness bug degrades to a wrong answer
// (diagnosable absmax failure) instead of a container-killing hang
#define SPIN_LIMIT (1u << 25)

__device__ __forceinline__ unsigned short f2b(float x) {
    // fp32 -> bf16 round-to-nearest-even
    unsigned u = __float_as_uint(x);
    return (unsigned short)((u + 0x7fffu + ((u >> 16) & 1u)) >> 16);
}
__device__ __forceinline__ float sigm(float x) {
    return __builtin_amdgcn_rcpf(1.0f + __expf(-x));
}
__device__ __forceinline__ float tanh_f(float x) {
    float e = __expf(2.0f * x);
    return 1.0f - 2.0f * __builtin_amdgcn_rcpf(1.0f + e);
}

// write-through system-scope stores: at MALL once vmcnt retires
__device__ __forceinline__ void store_short_wt(unsigned short* p, unsigned v) {
    asm volatile("global_store_short %0, %1, off sc0 sc1" :: "v"(p), "v"(v) : "memory");
}
__device__ __forceinline__ void store_dword_wt(float* p, float v) {
    asm volatile("global_store_dword %0, %1, off sc0 sc1" :: "v"(p), "v"(__float_as_uint(v)) : "memory");
}
__device__ __forceinline__ void store_u64_wt(unsigned long long* p, unsigned long long v) {
    asm volatile("global_store_dwordx2 %0, %1, off sc0 sc1" :: "v"(p), "v"(v) : "memory");
}
// Poll via atomic RMW(+0): the ONLY read primitive proven promptly coherent
// cross-XCD for atomically-updated lines (R1-R6 ablation). asm because
// InstCombine turns fetch_add(p,0) back into a plain atomic load.
__device__ __forceinline__ unsigned poll_read(unsigned* p) {
    unsigned old;
    asm volatile("global_atomic_add %0, %1, %2, off sc0 sc1\n\ts_waitcnt vmcnt(0)"
                 : "=v"(old) : "v"(p), "v"(0u) : "memory");
    return old;
}
// fresh h read: relaxed system-scope atomic load = global_load_dwordx2 sc0 sc1
// (bypasses L1/L2 -> reads MALL where WT stores land; compiler-tracked vmcnt).
__device__ __forceinline__ unsigned long long load_u64_bypass(const unsigned short* p) {
    return __hip_atomic_load((const unsigned long long*)p,
                             __ATOMIC_RELAXED, __HIP_MEMORY_SCOPE_SYSTEM);
}

// h fragment layout: h_f[kk][mt][laneF][e], kk=k>>5, mt=b>>4,
// laneF=((k>>3)&3)*16+(b&15), e=k&7. One MFMA A-frag = 64 lanes x 16B contig.
__device__ __forceinline__ long hfrag_off(int b, int k) {
    return ((long)(((k >> 5) * 4 + (b >> 4)) * 64) + ((k >> 3) & 3) * 16 + (b & 15)) * 8 + (k & 7);
}

// Prep: init_hidden fp32 -> bf16 h0 (frag layout, WT stores so the MALL copy
// is authoritative for gru's bypass loads); zero barrier ctrl (WT too).
__global__ void prep_kernel(const float* __restrict__ init_h,
                            unsigned short* __restrict__ h0,
                            unsigned* __restrict__ ctrl) {
    const int i = blockIdx.x * 256 + threadIdx.x;  // 0..32767
    const int b  = i >> 9;
    const int k4 = (i & 511) << 2;
    float4 v = *reinterpret_cast<const float4*>(init_h + (long)b * Hn + k4);
    unsigned long long q = (unsigned long long)f2b(v.x)
                         | ((unsigned long long)f2b(v.y) << 16)
                         | ((unsigned long long)f2b(v.z) << 32)
                         | ((unsigned long long)f2b(v.w) << 48);
    store_u64_wt((unsigned long long*)(h0 + hfrag_off(b, k4)), q);
    if (i < 2048)
        asm volatile("global_store_dword %0, %1, off sc0 sc1"
                     :: "v"(ctrl + i), "v"(0u) : "memory");
}

// Persistent GRU. 128 blocks x 512 threads (8 waves).
// Block bk owns 16 hidden units j in [16*bk, 16*bk+16).
// Wave w owns K-slice [256w, 256w+256); W rows live in REGISTERS (Bf[3][8]).
// K-loop uses 16-load BURSTS for memory-level parallelism: 16 independent 8B
// bypass loads back-to-back into registers (hb[16] = 32 VGPRs), then 24
// MFMAs; 4 bursts/step. (R9: interleaved load->MFMA serialized ~32 MALL RTTs
// ~8us/step. R10's 32-load burst needed ~258 VGPRs > 256 cap from
// __launch_bounds__(512,2) -> launch failure -> container kill. 16-load burst
// fits: ~226 VGPRs.)
// TWO-ROUND LDS reduction (48 KB; >64 KB static LDS kills launch, R7/R8).
// fp32 hidden state in registers at MFMA C-layout positions.
// NO fences / NO cache maintenance anywhere in the hot loop (R5 lesson).
// Barrier: leaf arrive RMW -> closer root RMW -> closers poll root counter ->
// leaf flag RMW -> members poll. All signals RMW, all polls RMW(+0).
__global__ void __launch_bounds__(NTHR, 2) gru_kernel(
    const float* __restrict__ inp,     // [T][B][3]
    const float* __restrict__ init_h,  // [B][H]
    const float* __restrict__ w_ih,    // [3H][3]
    const float* __restrict__ w_hh,    // [3H][H] fp32
    const float* __restrict__ bias,    // [3H]
    const float* __restrict__ bias_n,  // [H]
    unsigned short* __restrict__ h0,   // [B][H] bf16 frag-layout double buffer
    unsigned short* __restrict__ h1,
    unsigned* __restrict__ ctrl,       // [2048] barrier counters + flags
    float* __restrict__ out)           // [T][B]
{
    __shared__ f32x4 red[4][4][3][64];  // [src][mt][nt][lane] = 48 KB

    const int tid  = threadIdx.x;
    const int lane = tid & 63;
    const int w    = tid >> 6;      // wave id = K-slice owner
    const int quad = lane >> 4;
    const int n16  = lane & 15;
    const int j0   = blockIdx.x * 16;
    const int jg   = j0 + n16;      // this lane's hidden column (epilogue)
    const int ks   = w * 256;

    // ---- preload W rows into registers as bf16 B-fragments (one-time) ----
    bf16x8 Bf[3][8];
    #pragma unroll
    for (int nt = 0; nt < 3; ++nt) {
        const long row = (long)(nt * Hn + j0 + n16);
        #pragma unroll
        for (int k = 0; k < 8; ++k) {
            const float* p = w_hh + row * Hn + ks + k * 32 + quad * 8;
            bf16x8 b;
            #pragma unroll
            for (int j = 0; j < 8; ++j) b[j] = (short)f2b(p[j]);
            Bf[nt][k] = b;
        }
    }

    // Epilogue constants (used by waves 0-3; all 64 lanes active)
    float wr0 = w_ih[jg*3+0], wr1 = w_ih[jg*3+1], wr2 = w_ih[jg*3+2];
    float wz0 = w_ih[(Hn+jg)*3+0], wz1 = w_ih[(Hn+jg)*3+1], wz2 = w_ih[(Hn+jg)*3+2];
    float wn0 = w_ih[(2*Hn+jg)*3+0], wn1 = w_ih[(2*Hn+jg)*3+1], wn2 = w_ih[(2*Hn+jg)*3+2];
    float br_ = bias[jg], bz_ = bias[Hn+jg], bn2_ = bias[2*Hn+jg];
    float bnn_ = bias_n[jg];

    // fp32 hidden state (waves 0-3; batch b = 16*w + quad*4 + r, col jg)
    float hst[4];
    if (w < 4) {
        #pragma unroll
        for (int r = 0; r < 4; ++r)
            hst[r] = init_h[(long)(16 * w + quad * 4 + r) * Hn + jg];
    }

    // epilogue frag-store decomposition of j = 16*bid + n16
    const int kkE = blockIdx.x >> 1;            // j>>5 (lane-uniform)
    const int qE  = (blockIdx.x & 1) * 2 + (n16 >> 3);
    const int eE  = n16 & 7;

    const int leaf = blockIdx.x >> 3;           // 16 leaves x 8 blocks

    for (int t = 0; t < Tn; ++t) {
        const unsigned short* hcur = (t & 1) ? h1 : h0;
        unsigned short* hnext      = (t & 1) ? h0 : h1;

        // input contributions for this step (cached loads; inp is read-only)
        float xv[4][3];
        if (w < 4) {
            #pragma unroll
            for (int r = 0; r < 4; ++r) {
                const float* xp = inp + ((long)t * Bn + 16 * w + quad * 4 + r) * 3;
                xv[r][0] = xp[0]; xv[r][1] = xp[1]; xv[r][2] = xp[2];
            }
        }

        f32x4 acc[4][3];
        #pragma unroll
        for (int mt = 0; mt < 4; ++mt)
            #pragma unroll
            for (int nt = 0; nt < 3; ++nt)
                acc[mt][nt] = f32x4{0.f, 0.f, 0.f, 0.f};

        // wave's A-frag base: frag f=(k*4+mt) at short-offset f*512 + lane*8
        const unsigned short* pa = hcur + (long)(w * 8 * 4 * 64 + lane) * 8;

        // ---- 4 bursts: 16 loads back-to-back (2 k-values), then 24 MFMAs ----
        #pragma unroll
        for (int kb = 0; kb < 4; ++kb) {
            unsigned long long hb[16];
            const unsigned short* ph = pa + (long)(kb * 8) * 512;
            #pragma unroll
            for (int f = 0; f < 8; ++f) {
                hb[2*f]   = load_u64_bypass(ph + (long)f * 512);
                hb[2*f+1] = load_u64_bypass(ph + (long)f * 512 + 4);
            }
            #pragma unroll
            for (int k2 = 0; k2 < 2; ++k2) {
                const int k = kb * 2 + k2;
                #pragma unroll
                for (int mt = 0; mt < 4; ++mt) {
                    const int f = k2 * 4 + mt;
                    union { unsigned long long q[2]; bf16x8 v; } u;
                    u.q[0] = hb[2*f]; u.q[1] = hb[2*f+1];
                    bf16x8 a = u.v;
                    acc[mt][0] = __builtin_amdgcn_mfma_f32_16x16x32_bf16(a, Bf[0][k], acc[mt][0], 0, 0, 0);
                    acc[mt][1] = __builtin_amdgcn_mfma_f32_16x16x32_bf16(a, Bf[1][k], acc[mt][1], 0, 0, 0);
                    acc[mt][2] = __builtin_amdgcn_mfma_f32_16x16x32_bf16(a, Bf[2][k], acc[mt][2], 0, 0, 0);
                }
            }
        }

        // ---- two-round cross-wave K reduction through LDS (48 KB) ----
        if (w >= 4) {
            #pragma unroll
            for (int mt = 0; mt < 4; ++mt)
                #pragma unroll
                for (int nt = 0; nt < 3; ++nt)
                    red[w - 4][mt][nt][lane] = acc[mt][nt];
        }
        __syncthreads();
        if (w < 4) {
            #pragma unroll
            for (int mt = 0; mt < 4; ++mt)
                #pragma unroll
                for (int nt = 0; nt < 3; ++nt)
                    acc[mt][nt] += red[w][mt][nt][lane];
        }
        __syncthreads();
        if (w < 4) {
            #pragma unroll
            for (int mt = 0; mt < 4; ++mt)
                #pragma unroll
                for (int nt = 0; nt < 3; ++nt)
                    red[w][mt][nt][lane] = acc[mt][nt];
        }
        __syncthreads();

        if (w < 4) {
            f32x4 s0 = red[0][w][0][lane], s1 = red[0][w][1][lane], s2 = red[0][w][2][lane];
            #pragma unroll
            for (int src = 1; src < 4; ++src) {
                s0 += red[src][w][0][lane];
                s1 += red[src][w][1][lane];
                s2 += red[src][w][2][lane];
            }
            #pragma unroll
            for (int r = 0; r < 4; ++r) {
                const int b = 16 * w + quad * 4 + r;
                float pr = br_ + wr0*xv[r][0] + wr1*xv[r][1] + wr2*xv[r][2] + s0[r];
                float pz = bz_ + wz0*xv[r][0] + wz1*xv[r][1] + wz2*xv[r][2] + s1[r];
                float rr = sigm(pr);
                float zz = sigm(pz);
                float pn = bn2_ + wn0*xv[r][0] + wn1*xv[r][1] + wn2*xv[r][2] + rr * (s2[r] + bnn_);
                float nn = tanh_f(pn);
                float hv = nn + zz * (hst[r] - nn);
                hst[r] = hv;
                store_short_wt(hnext + ((long)((kkE * 4 + w) * 64) + qE * 16 + quad * 4 + r) * 8 + eE,
                               (unsigned)f2b(hv));
                if (blockIdx.x == 0 && n16 == 0)
                    store_dword_wt(out + t * Bn + b, hv);
            }
        }

        // ---- grid barrier: all signals via RMW, all polls via RMW(+0) ----
        __syncthreads();   // drains vmcnt(0) per wave -> WT stores at MALL
        if (tid == 0) {
            const unsigned tgt = (unsigned)(t + 1);
            unsigned old = __hip_atomic_fetch_add(&ctrl[LEAF_CTR(leaf)], 1u,
                                                  __ATOMIC_RELAXED, __HIP_MEMORY_SCOPE_SYSTEM);
            unsigned spins = 0;
            if ((old & 7) == 7) {      // this block closed its leaf
                __hip_atomic_fetch_add(&ctrl[ROOT_CTR], 1u,
                                       __ATOMIC_RELAXED, __HIP_MEMORY_SCOPE_SYSTEM);
                // poll the root COUNTER directly (no flag hop): 16 pollers
                while (poll_read(&ctrl[ROOT_CTR]) < 16u * tgt) {
                    __builtin_amdgcn_s_sleep(1);
                    if (++spins > SPIN_LIMIT) break;   // watchdog
                }
                __hip_atomic_fetch_add(&ctrl[LEAF_FLAG(leaf)], 1u,
                                       __ATOMIC_RELAXED, __HIP_MEMORY_SCOPE_SYSTEM);
            } else {
                while (poll_read(&ctrl[LEAF_FLAG(leaf)]) < tgt) {
                    __builtin_amdgcn_s_sleep(1);
                    if (++spins > SPIN_LIMIT) break;   // watchdog
                }
            }
        }
        __syncthreads();
    }
}

extern "C" void kernel_launch(void* const* d_in, const int* in_sizes, int n_in,
                              void* d_out, int out_size, void* d_ws, size_t ws_size,
                              hipStream_t stream) {
    const float* inp    = (const float*)d_in[0];  // [1024][64][3]
    const float* init_h = (const float*)d_in[1];  // [64][2048]
    const float* w_ih   = (const float*)d_in[2];  // [6144][3]
    const float* w_hh   = (const float*)d_in[3];  // [6144][2048]
    const float* bias   = (const float*)d_in[4];  // [6144]
    const float* bias_n = (const float*)d_in[5];  // [2048]
    float* out = (float*)d_out;                   // [1024][64]

    unsigned short* h0 = (unsigned short*)d_ws;          // 262144 B
    unsigned short* h1 = h0 + 131072L;                   // 262144 B
    unsigned* ctrl     = (unsigned*)(h1 + 131072L);      // 8192 B

    prep_kernel<<<128, 256, 0, stream>>>(init_h, h0, ctrl);
    gru_kernel<<<NBLK, NTHR, 0, stream>>>(inp, init_h, w_ih, w_hh, bias, bias_n,
                                          h0, h1, ctrl, out);
}